// Round 8
// baseline (2127.499 us; speedup 1.0000x reference)
//
#include <hip/hip_runtime.h>

#define BATCH 256
#define TSTEPS 4096
#define HID 136
#define HPADH 160     // h padded to 160 halves (320 B) = 5 K-tiles of 32
#define ODIM 68
#define NT 5          // N-tiles per wave (wave1's 5th tile is a zero dummy)
#define THREADS 128   // 2 waves: wave0 -> N-tiles 0..4, wave1 -> 5..8 (+dummy 9)

typedef _Float16 half8 __attribute__((ext_vector_type(8)));
typedef float f32x4 __attribute__((ext_vector_type(4)));
union H8U4 { uint4 u; half8 h; };

__device__ __forceinline__ float fast_tanh(float z) {
    float az = fabsf(z);
    float e = __expf(-2.0f * az);
    float r = (1.0f - e) * __builtin_amdgcn_rcpf(1.0f + e);
    return copysignf(r, z);
}

// One step: read A-frags (5x ds_read_b128, 16B broadcast per 16-lane group),
// 25 MFMA (5 N-tiles x 5 K-tiles, f32 accum), epilogue z/tanh on lanes 0..15,
// masked ds_write_b16 of new h. One barrier.
#define RNN_STEP(HR, HW, T)                                                    \
    {                                                                          \
        float2 xv = *(const float2*)(xs + 2 * (T));                            \
        H8U4 a0, a1, a2, a3, a4;                                               \
        a0.u = *(const uint4*)((const char*)(HR) + 0 * 64 + kb);               \
        a1.u = *(const uint4*)((const char*)(HR) + 1 * 64 + kb);               \
        a2.u = *(const uint4*)((const char*)(HR) + 2 * 64 + kb);               \
        a3.u = *(const uint4*)((const char*)(HR) + 3 * 64 + kb);               \
        a4.u = *(const uint4*)((const char*)(HR) + 4 * 64 + kb);               \
        _Pragma("unroll")                                                      \
        for (int i = 0; i < NT; ++i) {                                         \
            f32x4 c = {0.f, 0.f, 0.f, 0.f};                                    \
            c = __builtin_amdgcn_mfma_f32_16x16x32_f16(a0.h, bf[i][0], c, 0, 0, 0); \
            c = __builtin_amdgcn_mfma_f32_16x16x32_f16(a1.h, bf[i][1], c, 0, 0, 0); \
            c = __builtin_amdgcn_mfma_f32_16x16x32_f16(a2.h, bf[i][2], c, 0, 0, 0); \
            c = __builtin_amdgcn_mfma_f32_16x16x32_f16(a3.h, bf[i][3], c, 0, 0, 0); \
            c = __builtin_amdgcn_mfma_f32_16x16x32_f16(a4.h, bf[i][4], c, 0, 0, 0); \
            float z = c[0] + fmaf(xv.x, wx0[i], fmaf(xv.y, wx1[i], bs[i]));    \
            float th = fast_tanh(z);                                           \
            const int n = (wv * NT + i) * 16 + col;                            \
            if (lane < 16 && n < HID) ((_Float16*)(HW))[n] = (_Float16)th;     \
        }                                                                      \
        __syncthreads();                                                       \
    }

__global__ __launch_bounds__(THREADS)
void rnn_mfma_kernel(const float* __restrict__ x,
                     const float* __restrict__ W_ih,
                     const float* __restrict__ W_hh,
                     const float* __restrict__ b_ih,
                     const float* __restrict__ b_hh,
                     const float* __restrict__ W_fc,
                     const float* __restrict__ b_fc,
                     float* __restrict__ out)
{
    __shared__ __align__(16) float xs[TSTEPS * 2];   // 32 KB: x[b,:,:]
    __shared__ __align__(16) _Float16 hA[HPADH];     // 320 B, [136..160) == 0
    __shared__ __align__(16) _Float16 hB[HPADH];

    const int b    = blockIdx.x;
    const int tid  = threadIdx.x;
    const int lane = tid & 63;
    const int wv   = tid >> 6;        // wave 0 or 1
    const int col  = lane & 15;       // N-col within tile (and A-row id)
    const int kgrp = lane >> 4;       // k-group 0..3 (8 k's each)
    const int kb   = kgrp * 16;       // byte offset of this lane's A 16B chunk

    // ---- register-resident B-frags: W_hh^T tiles, f16 ----
    // B[k][n] = W_hh[n][k]; lane holds B[tk*32 + kgrp*8 + j][tn*16 + col]
    half8 bf[NT][5];
    float wx0[NT], wx1[NT], bs[NT];
#pragma unroll
    for (int i = 0; i < NT; ++i) {
        const int n = (wv * NT + i) * 16 + col;
        const bool nv = (n < HID);
#pragma unroll
        for (int tk = 0; tk < 5; ++tk) {
#pragma unroll
            for (int j = 0; j < 8; ++j) {
                const int k = tk * 32 + kgrp * 8 + j;
                const float v = (nv && k < HID) ? W_hh[n * HID + k] : 0.0f;
                bf[i][tk][j] = (_Float16)v;
            }
        }
        wx0[i] = nv ? W_ih[n * 2 + 0] : 0.0f;
        wx1[i] = nv ? W_ih[n * 2 + 1] : 0.0f;
        bs[i]  = nv ? (b_ih[n] + b_hh[n]) : 0.0f;
    }

    // ---- stage x[b] into LDS (coalesced float4); zero h buffers ----
    {
        const float4* xg = (const float4*)(x + (size_t)b * (TSTEPS * 2));
        float4* xl = (float4*)xs;
#pragma unroll
        for (int i = 0; i < TSTEPS * 2 / 4 / THREADS; ++i)
            xl[i * THREADS + tid] = xg[i * THREADS + tid];
    }
    for (int i = tid; i < HPADH; i += THREADS) {
        hA[i] = (_Float16)0.f;
        hB[i] = (_Float16)0.f;
    }
    __syncthreads();

    // ---- recurrence, unrolled x2 (fixed buffers), 1 barrier per step ----
    for (int t = 0; t < TSTEPS; t += 2) {
        RNN_STEP(hA, hB, t);
        RNN_STEP(hB, hA, t + 1);
    }
    // TSTEPS even -> final h in hA

    // ---- final head: out[b][o] = h . W_fc[o,:] + b_fc[o] ----
    if (tid < ODIM) {
        const int o = tid;
        float s = b_fc[o];
#pragma unroll 8
        for (int k = 0; k < HID; ++k)
            s = fmaf((float)hA[k], W_fc[o * HID + k], s);
        out[b * ODIM + o] = s;
    }
}

extern "C" void kernel_launch(void* const* d_in, const int* in_sizes, int n_in,
                              void* d_out, int out_size, void* d_ws, size_t ws_size,
                              hipStream_t stream) {
    const float* x    = (const float*)d_in[0];
    const float* W_ih = (const float*)d_in[1];
    const float* W_hh = (const float*)d_in[2];
    const float* b_ih = (const float*)d_in[3];
    const float* b_hh = (const float*)d_in[4];
    const float* W_fc = (const float*)d_in[5];
    const float* b_fc = (const float*)d_in[6];
    float* out = (float*)d_out;

    rnn_mfma_kernel<<<BATCH, THREADS, 0, stream>>>(x, W_ih, W_hh, b_ih, b_hh,
                                                   W_fc, b_fc, out);
}